// Round 13
// baseline (253.308 us; speedup 1.0000x reference)
//
#include <hip/hip_runtime.h>
#include <hip/hip_bf16.h>

typedef __bf16 bf16;
typedef __attribute__((ext_vector_type(8))) __bf16 bf16x8;
typedef __attribute__((ext_vector_type(4))) float f32x4;

#define LAMBDA_INIT_F 0.3555090675909693f
#define RMS_EPS 1e-5f
// (1/sqrt(128)) * log2(e) : folded into Q so QK^T scores are ready for exp2
#define QSCALE_F 0.1275174053237f

__device__ __forceinline__ void gl_lds16(const bf16* g, bf16* l) {
  __builtin_amdgcn_global_load_lds(
      (const __attribute__((address_space(1))) unsigned int*)g,
      (__attribute__((address_space(3))) unsigned int*)l, 16, 0, 0);
}

// ---------------------------------------------------------------- fused cast f32 -> bf16
// Destinations contiguous in ws: Xb(4M) Wqb(2M) Wkb(2M) Wvb(2M) Wob(2M) elems.
// Wo region is pre-scaled by rms_scale[col&255] * (1-lambda_init).
__global__ void fused_cast(const float* __restrict__ X, const float* __restrict__ Wq,
                           const float* __restrict__ Wk, const float* __restrict__ Wv,
                           const float* __restrict__ Wo, const float* __restrict__ rs,
                           bf16* __restrict__ out) {
  constexpr int T4 = 3145728;          // 12M elems / 4
  constexpr float OSC = 1.0f - LAMBDA_INIT_F;
  int idx = blockIdx.x * blockDim.x + threadIdx.x;
  int stride = gridDim.x * blockDim.x;
  for (int i = idx; i < T4; i += stride) {
    const float* src;
    int off;
    bool isWo = false;
    if (i < 1048576)       { src = X;  off = i; }
    else if (i < 1572864)  { src = Wq; off = i - 1048576; }
    else if (i < 2097152)  { src = Wk; off = i - 1572864; }
    else if (i < 2621440)  { src = Wv; off = i - 2097152; }
    else                   { src = Wo; off = i - 2621440; isWo = true; }
    float4 v = reinterpret_cast<const float4*>(src)[off];
    if (isWo) {
      int r0 = (off * 4) & 255;        // col % 256 (row len 2048 divisible by 256)
      v.x *= rs[r0] * OSC; v.y *= rs[r0 + 1] * OSC;
      v.z *= rs[r0 + 2] * OSC; v.w *= rs[r0 + 3] * OSC;
    }
    bf16 o[4];
    o[0] = (bf16)v.x; o[1] = (bf16)v.y; o[2] = (bf16)v.z; o[3] = (bf16)v.w;
    *reinterpret_cast<ushort4*>(&out[(size_t)i * 4]) = *reinterpret_cast<const ushort4*>(o);
  }
}

// ---------------------------------------------------------------- bt-GEMM (global_load_lds, 2-phase dbuf)
// C[m,n] = sum_k A[m,k] * B[n,k]
// MODE 1: f32 row-major out.
// MODE 3: fused QKV epilogue (N=6144): region n>>11 == 0 -> Qb bf16 * QSCALE;
//         1 -> Kb bf16; 2 -> Vt[b,h,e, perm(nseq)] (key 16h+4g+c -> slot 8g+4h+c).
//         Region-2 blocks (bn>=4096) run the MFMA with SWAPPED operands so the
//         C/D fragment is transposed: lanes span 16 consecutive nq -> the permuted
//         V store becomes 16x8B segments per inst instead of 64x2B scatter.
template <int MODE, int BM>
__global__ __launch_bounds__(256) void gemm_bt(
    const bf16* __restrict__ A, const bf16* __restrict__ B,
    void* __restrict__ Cv, int M, int N, int K) {
  constexpr int BN = 128, BK = 32;
  constexpr int MF = BM / 32;
  constexpr int CA = BM / 16;
  __shared__ __align__(16) bf16 As[2][BM * BK];
  __shared__ __align__(16) bf16 Bs[2][BN * BK];
  const int tid = threadIdx.x, lane = tid & 63, w = tid >> 6;
  const int l15 = lane & 15, lhi = lane >> 4;
  const int wr = (w >> 1) * (BM / 2), wc = (w & 1) * 64;
  const int bm = blockIdx.x * BM, bn = blockIdx.y * BN;
  const int srow = lane >> 2, scol = (lane & 3) * 8;
  const int NTK = K / BK;
  const bool reg2 = (MODE == 3) && (bn >= 4096);
  f32x4 acc[MF][4] = {};

  auto stage = [&](int buf, int k0) {
#pragma unroll
    for (int i = 0; i < CA / 4; ++i) {
      int c = w * (CA / 4) + i;
      gl_lds16(&A[(size_t)(bm + c * 16 + srow) * K + k0 + scol], &As[buf][c * 512]);
    }
#pragma unroll
    for (int i = 0; i < 2; ++i) {
      int c = w * 2 + i;
      gl_lds16(&B[(size_t)(bn + c * 16 + srow) * K + k0 + scol], &Bs[buf][c * 512]);
    }
  };

  stage(0, 0);
  __syncthreads();
  for (int t = 0; t < NTK; ++t) {
    const int buf = t & 1;
    if (t + 1 < NTK) stage(buf ^ 1, (t + 1) * BK);
    bf16x8 af[MF], bfr[4];
#pragma unroll
    for (int mf = 0; mf < MF; ++mf)
      af[mf] = *reinterpret_cast<const bf16x8*>(&As[buf][(wr + mf * 16 + l15) * BK + lhi * 8]);
#pragma unroll
    for (int nf = 0; nf < 4; ++nf)
      bfr[nf] = *reinterpret_cast<const bf16x8*>(&Bs[buf][(wc + nf * 16 + l15) * BK + lhi * 8]);
    if (!reg2) {
#pragma unroll
      for (int mf = 0; mf < MF; ++mf)
#pragma unroll
        for (int nf = 0; nf < 4; ++nf)
          acc[mf][nf] = __builtin_amdgcn_mfma_f32_16x16x32_bf16(af[mf], bfr[nf], acc[mf][nf], 0, 0, 0);
    } else {
      // swapped operands: D[n][m] fragments (transposed) for coalesced Vt store
#pragma unroll
      for (int mf = 0; mf < MF; ++mf)
#pragma unroll
        for (int nf = 0; nf < 4; ++nf)
          acc[mf][nf] = __builtin_amdgcn_mfma_f32_16x16x32_bf16(bfr[nf], af[mf], acc[mf][nf], 0, 0, 0);
    }
    __syncthreads();
  }

#pragma unroll
  for (int mf = 0; mf < MF; ++mf)
#pragma unroll
    for (int nf = 0; nf < 4; ++nf)
#pragma unroll
      for (int r = 0; r < 4; ++r) {
        if constexpr (MODE == 1) {
          int m = bm + wr + mf * 16 + lhi * 4 + r;
          int n = bn + wc + nf * 16 + l15;
          ((float*)Cv)[(size_t)m * N + n] = acc[mf][nf][r];
        } else {
          if (!reg2) {
            int m = bm + wr + mf * 16 + lhi * 4 + r;
            int n = bn + wc + nf * 16 + l15;
            int reg = n >> 11, nl = n & 2047;
            if (reg == 0) {
              ((bf16*)Cv)[(size_t)m * 2048 + nl] = (bf16)(acc[mf][nf][r] * QSCALE_F);
            } else {
              ((bf16*)Cv)[(size_t)(m + 4096) * 2048 + nl] = (bf16)acc[mf][nf][r];
            }
          } else {
            // transposed fragment: row (lhi*4+r) = n side, col (l15) = m side
            int n = bn + wc + nf * 16 + lhi * 4 + r;
            int nl = n & 2047;
            int hh = nl >> 8, e = nl & 255;
            int m = bm + wr + mf * 16 + l15;
            int bb = m >> 11, nq = m & 2047;
            // slot-permute: k5 = (mf&1)*16 + l15 -> slot = 8*(l15>>2) + 4*(mf&1) + (l15&3)
            int np = (nq & ~31) | ((l15 >> 2) * 8 + (mf & 1) * 4 + (l15 & 3));
            ((bf16*)Cv)[(size_t)16777216 + ((((size_t)bb * 8 + hh) * 256 + e) << 11) + np] =
                (bf16)acc[mf][nf][r];
          }
        }
      }
}

// ---------------------------------------------------------------- differential flash attention
// 1D grid 512 (XCD-chunk swizzled), block 256 = 4 waves: q-group g=w>>1 (32 rows),
// stream s=w&1. q-tile = 64 rows. Each wave owns 32 q-rows of ONE stream as two
// 16-row halves: every K/V fragment read feeds 2 MFMAs (halved per-FLOP LDS traffic),
// P fully in-lane. Swapped QK^T; max-free softmax via exp2 (Q pre-scaled by SC*log2e);
// per-lane partial l per half, reduced in epilogue. K LDS [32][256] w/ 16B-slot XOR
// swizzle in gl_lds16 source; V slot-permuted global -> 16B-contiguous staging with
// chunk bank-swizzle. Double-buffered, one barrier/tile, stage pinned mid-iteration.
// RMS scale & (1-lambda_init) folded into Wo: epilogue applies rinv only.
__global__ __launch_bounds__(256, 2) void diff_attn(
    const bf16* __restrict__ Q, const bf16* __restrict__ Kb, const bf16* __restrict__ Vtg,
    const float* __restrict__ lq1, const float* __restrict__ lk1,
    const float* __restrict__ lq2, const float* __restrict__ lk2,
    bf16* __restrict__ Ob) {
  constexpr int NSEQ = 2048, E = 2048, KT = 32, NT = NSEQ / KT;
  __shared__ __align__(16) char smem[65536];   // 2 x (K 16KB + V 16KB); epilogue: Zb[2][32][256] bf16
  bf16* Zb = (bf16*)smem;

  const int tid = threadIdx.x, lane = tid & 63, w = tid >> 6;
  const int l15 = lane & 15, lhi = lane >> 4;
  const int g = w >> 1, s = w & 1;

  // XCD-chunk swizzle: XCD k owns orig [k*64, (k+1)*64) -> 2 head-instances per XCD
  const int bid = blockIdx.x;
  const int orig = (bid & 7) * 64 + (bid >> 3);
  const int bh = orig >> 5;
  const int qb = orig & 31;
  const int b = bh >> 3, h = bh & 7;
  const int q0 = qb * 64;

  float lam = 0.f;
  if (s) {
    float sl1 = 0.f, sl2 = 0.f;
    for (int i = 0; i < 128; ++i) {
      sl1 += lq1[h * 128 + i] * lk1[h * 128 + i];
      sl2 += lq2[h * 128 + i] * lk2[h * 128 + i];
    }
    lam = __expf(sl1) - __expf(sl2) + LAMBDA_INIT_F;
  }

  // Q frags for the wave's two q-halves (B-operand: col=q, k=lhi*8+j)
  const size_t qbase = ((size_t)b * NSEQ + q0 + g * 32 + l15) * E + (size_t)h * 256 + s * 128;
  bf16x8 qlo[4], qhi[4];
#pragma unroll
  for (int df = 0; df < 4; ++df) {
    qlo[df] = *reinterpret_cast<const bf16x8*>(&Q[qbase + df * 32 + lhi * 8]);
    qhi[df] = *reinterpret_cast<const bf16x8*>(&Q[qbase + 16 * E + df * 32 + lhi * 8]);
  }

  const bf16* Kbase = Kb + ((size_t)b * NSEQ) * E + (size_t)h * 256;
  const bf16* Vbase = Vtg + (((size_t)b * 8 + h) * 256) * (size_t)NSEQ;

  // staging invariants
  const int krow_sub = lane >> 5;      // 0/1: row within 1KB K chunk
  const int kslot = lane & 31;         // 16B slot in 512B K row
  const int ve_sub = lane >> 2;        // 0..15: e-row within 1KB V chunk
  const int vchunk = lane & 3;         // 16B chunk within 64B V row
  const int swz = l15 & 7;
  const int vq2 = (l15 >> 1) & 3;      // V read swizzle key
  const int voff = (lhi ^ vq2) << 3;   // element offset of 16B within V row

  f32x4 olo[16] = {}, ohi[16] = {};
  float ll0 = 0.f, ll1 = 0.f;

  // 32 chunks of 1KB per tile (16 K + 16 V) over 4 waves: 8 per wave
  auto stage = [&](int buf, int t) {
    const int kt0 = t * KT;
    bf16* Ksl = (bf16*)(smem + buf * 32768);
    bf16* Vsl = Ksl + 8192;
    if (w < 2) {
#pragma unroll
      for (int i = 0; i < 8; ++i) {
        int c = w * 8 + i;
        int row = 2 * c + krow_sub;
        gl_lds16(&Kbase[(size_t)(kt0 + row) * E + ((kslot ^ (row & 7)) << 3)], &Ksl[c * 512]);
      }
    } else {
#pragma unroll
      for (int i = 0; i < 8; ++i) {
        int c = (w - 2) * 8 + i;
        int e = c * 16 + ve_sub;
        int lc = vchunk ^ ((e >> 1) & 3);
        gl_lds16(&Vbase[(size_t)e * NSEQ + kt0 + (lc << 3)], &Vsl[c * 512]);
      }
    }
  };

  stage(0, 0);
  __syncthreads();                     // tile 0 resident

  for (int t = 0; t < NT; ++t) {
    const int buf = t & 1;
    const bf16* Ksl = (const bf16*)(smem + buf * 32768);
    const bf16* Vsl = Ksl + 8192;

    // QK^T swapped: each kf feeds both q-halves
    f32x4 s0l = {}, s1l = {}, s0h = {}, s1h = {};
#pragma unroll
    for (int df = 0; df < 4; ++df) {
      const int slot = (((s << 4) + df * 4 + lhi) ^ swz) << 3;
      bf16x8 kf0 = *reinterpret_cast<const bf16x8*>(&Ksl[l15 * 256 + slot]);
      bf16x8 kf1 = *reinterpret_cast<const bf16x8*>(&Ksl[(16 + l15) * 256 + slot]);
      s0l = __builtin_amdgcn_mfma_f32_16x16x32_bf16(kf0, qlo[df], s0l, 0, 0, 0);
      s0h = __builtin_amdgcn_mfma_f32_16x16x32_bf16(kf0, qhi[df], s0h, 0, 0, 0);
      s1l = __builtin_amdgcn_mfma_f32_16x16x32_bf16(kf1, qlo[df], s1l, 0, 0, 0);
      s1h = __builtin_amdgcn_mfma_f32_16x16x32_bf16(kf1, qhi[df], s1h, 0, 0, 0);
    }

    // prefetch next tile: pinned so QK^T starts at barrier-exit; staging issue
    // overlaps the exp2 chain below.
    __builtin_amdgcn_sched_barrier(0);
    if (t + 1 < NT) stage(buf ^ 1, t + 1);
    __builtin_amdgcn_sched_barrier(0);

    // max-free softmax: P = 2^S for both q-halves
    bf16 pbl[8], pbh[8];
    float r0 = 0.f, r1 = 0.f;
#pragma unroll
    for (int r = 0; r < 4; ++r) {
      float e0 = __builtin_amdgcn_exp2f(s0l[r]);
      float e1 = __builtin_amdgcn_exp2f(s1l[r]);
      r0 += e0 + e1;
      pbl[r] = (bf16)e0;
      pbl[4 + r] = (bf16)e1;
      float e2 = __builtin_amdgcn_exp2f(s0h[r]);
      float e3 = __builtin_amdgcn_exp2f(s1h[r]);
      r1 += e2 + e3;
      pbh[r] = (bf16)e2;
      pbh[4 + r] = (bf16)e3;
    }
    ll0 += r0;
    ll1 += r1;
    bf16x8 pal = *reinterpret_cast<const bf16x8*>(pbl);
    bf16x8 pah = *reinterpret_cast<const bf16x8*>(pbh);

    __builtin_amdgcn_s_setprio(1);
#pragma unroll
    for (int eb = 0; eb < 16; ++eb) {
      bf16x8 vf = *reinterpret_cast<const bf16x8*>(&Vsl[(eb * 16 + l15) * 32 + voff]);
      olo[eb] = __builtin_amdgcn_mfma_f32_16x16x32_bf16(pal, vf, olo[eb], 0, 0, 0);
      ohi[eb] = __builtin_amdgcn_mfma_f32_16x16x32_bf16(pah, vf, ohi[eb], 0, 0, 0);
    }
    __builtin_amdgcn_s_setprio(0);

    __syncthreads();                   // drains next-tile loads; frees buf for overwrite
  }

  // epilogue: reduce l per half, cross-wave stream combine (bf16 Z) + RMS rinv + store
  ll0 += __shfl_xor(ll0, 16, 64);
  ll0 += __shfl_xor(ll0, 32, 64);
  ll1 += __shfl_xor(ll1, 16, 64);
  ll1 += __shfl_xor(ll1, 32, 64);
  float L0[4], L1[4];
#pragma unroll
  for (int r = 0; r < 4; ++r) {
    L0[r] = __shfl(ll0, 4 * lhi + r, 64);
    L1[r] = __shfl(ll1, 4 * lhi + r, 64);
  }

  bf16* Zg = Zb + g * 8192;            // [32 rows][256 e] bf16
  if (s) {
#pragma unroll
    for (int r = 0; r < 4; ++r) {
      float i2l = lam / L0[r];
      float i2h = lam / L1[r];
#pragma unroll
      for (int eb = 0; eb < 16; ++eb) {
        Zg[(4 * lhi + r) * 256 + eb * 16 + l15] = (bf16)(olo[eb][r] * i2l);
        Zg[(16 + 4 * lhi + r) * 256 + eb * 16 + l15] = (bf16)(ohi[eb][r] * i2h);
      }
    }
  }
  __syncthreads();
  if (!s) {
#pragma unroll
    for (int half = 0; half < 2; ++half) {
      const f32x4* oh = half ? ohi : olo;
      const float* Lh = half ? L1 : L0;
#pragma unroll
      for (int r = 0; r < 4; ++r) {
        float i1 = 1.0f / Lh[r];
        float vals[16];
        float ssq = 0.f;
#pragma unroll
        for (int eb = 0; eb < 16; ++eb) {
          float v = oh[eb][r] * i1 -
                    (float)Zg[(half * 16 + 4 * lhi + r) * 256 + eb * 16 + l15];
          vals[eb] = v;
          ssq += v * v;
        }
#pragma unroll
        for (int off = 1; off < 16; off <<= 1) ssq += __shfl_xor(ssq, off, 64);
        float rinv = rsqrtf(ssq * (1.0f / 256.0f) + RMS_EPS);
        const int q = q0 + g * 32 + half * 16 + 4 * lhi + r;
        const size_t ob = ((size_t)b * NSEQ + q) * E + (size_t)h * 256;
#pragma unroll
        for (int eb = 0; eb < 16; ++eb) {
          int e = eb * 16 + l15;
          Ob[ob + e] = (bf16)(vals[eb] * rinv);
        }
      }
    }
  }
}

// ---------------------------------------------------------------- launch
extern "C" void kernel_launch(void* const* d_in, const int* in_sizes, int n_in,
                              void* d_out, int out_size, void* d_ws, size_t ws_size,
                              hipStream_t stream) {
  const float* X   = (const float*)d_in[0];
  const float* Wq  = (const float*)d_in[1];
  const float* Wk  = (const float*)d_in[2];
  const float* Wv  = (const float*)d_in[3];
  const float* Wo  = (const float*)d_in[4];
  const float* lq1 = (const float*)d_in[5];
  const float* lk1 = (const float*)d_in[6];
  const float* lq2 = (const float*)d_in[7];
  const float* lk2 = (const float*)d_in[8];
  const float* rs  = (const float*)d_in[9];
  float* out = (float*)d_out;

  constexpr size_t B = 2, NSEQ = 2048, D = 1024, E = 2048;
  constexpr size_t M = B * NSEQ;  // 4096

  char* ws = (char*)d_ws;
  bf16* Xb  = (bf16*)ws;                 // M*D
  bf16* Wqb = Xb + M * D;                // E*D  (Wqb/Wkb/Wvb contiguous -> [6144][1024])
  bf16* Wkb = Wqb + E * D;
  bf16* Wvb = Wkb + E * D;
  bf16* Wob = Wvb + E * D;               // D*E (pre-scaled by rs*osc)
  bf16* Qb  = Wob + D * E;               // M*E  (Qb/Kb/Vtb contiguous for fused epilogue)
  bf16* Kb  = Qb + M * E;
  bf16* Vtb = Kb + M * E;                // M*E, layout [b,h,e,perm(n)]
  bf16* Ob  = Vtb + M * E;               // M*E

  fused_cast<<<2048, 256, 0, stream>>>(X, Wq, Wk, Wv, Wo, rs, Xb);

  gemm_bt<3, 128><<<dim3(M / 128, 6144 / 128), 256, 0, stream>>>(
      Xb, Wqb, Qb, (int)M, 6144, (int)D);

  diff_attn<<<dim3(512), 256, 0, stream>>>(Qb, Kb, Vtb, lq1, lk1, lq2, lk2, Ob);

  gemm_bt<1, 64><<<dim3(M / 64, D / 128), 256, 0, stream>>>(Ob, Wob, out, (int)M, (int)D, (int)E);
}

// Round 14
// 231.922 us; speedup vs baseline: 1.0922x; 1.0922x over previous
//
#include <hip/hip_runtime.h>
#include <hip/hip_bf16.h>

typedef __bf16 bf16;
typedef __attribute__((ext_vector_type(8))) __bf16 bf16x8;
typedef __attribute__((ext_vector_type(4))) float f32x4;

#define LAMBDA_INIT_F 0.3555090675909693f
#define RMS_EPS 1e-5f
// (1/sqrt(128)) * log2(e) : folded into Q so QK^T scores are ready for exp2
#define QSCALE_F 0.1275174053237f

__device__ __forceinline__ void gl_lds16(const bf16* g, bf16* l) {
  __builtin_amdgcn_global_load_lds(
      (const __attribute__((address_space(1))) unsigned int*)g,
      (__attribute__((address_space(3))) unsigned int*)l, 16, 0, 0);
}

// ---------------------------------------------------------------- fused cast f32 -> bf16
// Destinations contiguous in ws: Xb(4M) Wqb(2M) Wkb(2M) Wvb(2M) Wob(2M) elems.
// Wo region is pre-scaled by rms_scale[col&255] * (1-lambda_init).
__global__ void fused_cast(const float* __restrict__ X, const float* __restrict__ Wq,
                           const float* __restrict__ Wk, const float* __restrict__ Wv,
                           const float* __restrict__ Wo, const float* __restrict__ rs,
                           bf16* __restrict__ out) {
  constexpr int T4 = 3145728;          // 12M elems / 4
  constexpr float OSC = 1.0f - LAMBDA_INIT_F;
  int idx = blockIdx.x * blockDim.x + threadIdx.x;
  int stride = gridDim.x * blockDim.x;
  for (int i = idx; i < T4; i += stride) {
    const float* src;
    int off;
    bool isWo = false;
    if (i < 1048576)       { src = X;  off = i; }
    else if (i < 1572864)  { src = Wq; off = i - 1048576; }
    else if (i < 2097152)  { src = Wk; off = i - 1572864; }
    else if (i < 2621440)  { src = Wv; off = i - 2097152; }
    else                   { src = Wo; off = i - 2621440; isWo = true; }
    float4 v = reinterpret_cast<const float4*>(src)[off];
    if (isWo) {
      int r0 = (off * 4) & 255;        // col % 256 (row len 2048 divisible by 256)
      v.x *= rs[r0] * OSC; v.y *= rs[r0 + 1] * OSC;
      v.z *= rs[r0 + 2] * OSC; v.w *= rs[r0 + 3] * OSC;
    }
    bf16 o[4];
    o[0] = (bf16)v.x; o[1] = (bf16)v.y; o[2] = (bf16)v.z; o[3] = (bf16)v.w;
    *reinterpret_cast<ushort4*>(&out[(size_t)i * 4]) = *reinterpret_cast<const ushort4*>(o);
  }
}

// ---------------------------------------------------------------- bt-GEMM (global_load_lds, 2-phase dbuf)
// C[m,n] = sum_k A[m,k] * B[n,k]
// MODE 1: f32 row-major out.
// MODE 3: fused QKV epilogue (N=6144): region n>>11 == 0 -> Qb bf16 * QSCALE;
//         1 -> Kb bf16; 2 -> Vt[b,h,e, perm(nseq)] (key 16h+4g+c -> slot 8g+4h+c,
//         so attention's V staging is 16B-contiguous gl_lds16).
template <int MODE, int BM>
__global__ __launch_bounds__(256) void gemm_bt(
    const bf16* __restrict__ A, const bf16* __restrict__ B,
    void* __restrict__ Cv, int M, int N, int K) {
  constexpr int BN = 128, BK = 32;
  constexpr int MF = BM / 32;
  constexpr int CA = BM / 16;
  __shared__ __align__(16) bf16 As[2][BM * BK];
  __shared__ __align__(16) bf16 Bs[2][BN * BK];
  const int tid = threadIdx.x, lane = tid & 63, w = tid >> 6;
  const int l15 = lane & 15, lhi = lane >> 4;
  const int wr = (w >> 1) * (BM / 2), wc = (w & 1) * 64;
  const int bm = blockIdx.x * BM, bn = blockIdx.y * BN;
  const int srow = lane >> 2, scol = (lane & 3) * 8;
  const int NTK = K / BK;
  f32x4 acc[MF][4] = {};

  auto stage = [&](int buf, int k0) {
#pragma unroll
    for (int i = 0; i < CA / 4; ++i) {
      int c = w * (CA / 4) + i;
      gl_lds16(&A[(size_t)(bm + c * 16 + srow) * K + k0 + scol], &As[buf][c * 512]);
    }
#pragma unroll
    for (int i = 0; i < 2; ++i) {
      int c = w * 2 + i;
      gl_lds16(&B[(size_t)(bn + c * 16 + srow) * K + k0 + scol], &Bs[buf][c * 512]);
    }
  };

  stage(0, 0);
  __syncthreads();
  for (int t = 0; t < NTK; ++t) {
    const int buf = t & 1;
    if (t + 1 < NTK) stage(buf ^ 1, (t + 1) * BK);
    bf16x8 af[MF], bfr[4];
#pragma unroll
    for (int mf = 0; mf < MF; ++mf)
      af[mf] = *reinterpret_cast<const bf16x8*>(&As[buf][(wr + mf * 16 + l15) * BK + lhi * 8]);
#pragma unroll
    for (int nf = 0; nf < 4; ++nf)
      bfr[nf] = *reinterpret_cast<const bf16x8*>(&Bs[buf][(wc + nf * 16 + l15) * BK + lhi * 8]);
#pragma unroll
    for (int mf = 0; mf < MF; ++mf)
#pragma unroll
      for (int nf = 0; nf < 4; ++nf)
        acc[mf][nf] = __builtin_amdgcn_mfma_f32_16x16x32_bf16(af[mf], bfr[nf], acc[mf][nf], 0, 0, 0);
    __syncthreads();
  }

#pragma unroll
  for (int mf = 0; mf < MF; ++mf)
#pragma unroll
    for (int nf = 0; nf < 4; ++nf)
#pragma unroll
      for (int r = 0; r < 4; ++r) {
        int m = bm + wr + mf * 16 + lhi * 4 + r;
        int n = bn + wc + nf * 16 + l15;
        if constexpr (MODE == 1) {
          ((float*)Cv)[(size_t)m * N + n] = acc[mf][nf][r];
        } else {
          int reg = n >> 11, nl = n & 2047;
          if (reg == 0) {
            ((bf16*)Cv)[(size_t)m * 2048 + nl] = (bf16)(acc[mf][nf][r] * QSCALE_F);
          } else if (reg == 1) {
            ((bf16*)Cv)[(size_t)(m + 4096) * 2048 + nl] = (bf16)acc[mf][nf][r];
          } else {
            // Vt[b, h, e, perm(nseq)] at Cv + 2*M*2048
            int bb = m >> 11, nq = m & 2047;
            int hh = nl >> 8, e = nl & 255;
            int k5 = nq & 31;
            int slot = (((k5 >> 2) & 3) << 3) | (((k5 >> 4) & 1) << 2) | (k5 & 3);
            int np = (nq & ~31) | slot;
            ((bf16*)Cv)[(size_t)16777216 + ((((size_t)bb * 8 + hh) * 256 + e) << 11) + np] =
                (bf16)acc[mf][nf][r];
          }
        }
      }
}

// ---------------------------------------------------------------- differential flash attention
// 1D grid 512 (XCD-chunk swizzled), block 256 = 4 waves: q-group g=w>>1 (32 rows),
// stream s=w&1. q-tile = 64 rows. Each wave owns 32 q-rows of ONE stream as two
// 16-row halves: every K/V fragment read feeds 2 MFMAs (halved per-FLOP LDS traffic),
// P fully in-lane. Swapped QK^T; max-free softmax via exp2 (Q pre-scaled by SC*log2e);
// per-lane partial l per half, reduced in epilogue. K LDS [32][256] w/ 16B-slot XOR
// swizzle in gl_lds16 source; V slot-permuted global -> 16B-contiguous staging with
// chunk bank-swizzle. Double-buffered, one barrier/tile, stage pinned mid-iteration.
// RMS scale & (1-lambda_init) folded into Wo: epilogue applies rinv only.
__global__ __launch_bounds__(256, 2) void diff_attn(
    const bf16* __restrict__ Q, const bf16* __restrict__ Kb, const bf16* __restrict__ Vtg,
    const float* __restrict__ lq1, const float* __restrict__ lk1,
    const float* __restrict__ lq2, const float* __restrict__ lk2,
    bf16* __restrict__ Ob) {
  constexpr int NSEQ = 2048, E = 2048, KT = 32, NT = NSEQ / KT;
  __shared__ __align__(16) char smem[65536];   // 2 x (K 16KB + V 16KB); epilogue: Zb[2][32][256] bf16
  bf16* Zb = (bf16*)smem;

  const int tid = threadIdx.x, lane = tid & 63, w = tid >> 6;
  const int l15 = lane & 15, lhi = lane >> 4;
  const int g = w >> 1, s = w & 1;

  // XCD-chunk swizzle: XCD k owns orig [k*64, (k+1)*64) -> 2 head-instances per XCD
  const int bid = blockIdx.x;
  const int orig = (bid & 7) * 64 + (bid >> 3);
  const int bh = orig >> 5;
  const int qb = orig & 31;
  const int b = bh >> 3, h = bh & 7;
  const int q0 = qb * 64;

  float lam = 0.f;
  if (s) {
    float sl1 = 0.f, sl2 = 0.f;
    for (int i = 0; i < 128; ++i) {
      sl1 += lq1[h * 128 + i] * lk1[h * 128 + i];
      sl2 += lq2[h * 128 + i] * lk2[h * 128 + i];
    }
    lam = __expf(sl1) - __expf(sl2) + LAMBDA_INIT_F;
  }

  // Q frags for the wave's two q-halves (B-operand: col=q, k=lhi*8+j)
  const size_t qbase = ((size_t)b * NSEQ + q0 + g * 32 + l15) * E + (size_t)h * 256 + s * 128;
  bf16x8 qlo[4], qhi[4];
#pragma unroll
  for (int df = 0; df < 4; ++df) {
    qlo[df] = *reinterpret_cast<const bf16x8*>(&Q[qbase + df * 32 + lhi * 8]);
    qhi[df] = *reinterpret_cast<const bf16x8*>(&Q[qbase + 16 * E + df * 32 + lhi * 8]);
  }

  const bf16* Kbase = Kb + ((size_t)b * NSEQ) * E + (size_t)h * 256;
  const bf16* Vbase = Vtg + (((size_t)b * 8 + h) * 256) * (size_t)NSEQ;

  // staging invariants
  const int krow_sub = lane >> 5;      // 0/1: row within 1KB K chunk
  const int kslot = lane & 31;         // 16B slot in 512B K row
  const int ve_sub = lane >> 2;        // 0..15: e-row within 1KB V chunk
  const int vchunk = lane & 3;         // 16B chunk within 64B V row
  const int swz = l15 & 7;
  const int vq2 = (l15 >> 1) & 3;      // V read swizzle key
  const int voff = (lhi ^ vq2) << 3;   // element offset of 16B within V row

  f32x4 olo[16] = {}, ohi[16] = {};
  float ll0 = 0.f, ll1 = 0.f;

  // 32 chunks of 1KB per tile (16 K + 16 V) over 4 waves: 8 per wave
  auto stage = [&](int buf, int t) {
    const int kt0 = t * KT;
    bf16* Ksl = (bf16*)(smem + buf * 32768);
    bf16* Vsl = Ksl + 8192;
    if (w < 2) {
#pragma unroll
      for (int i = 0; i < 8; ++i) {
        int c = w * 8 + i;
        int row = 2 * c + krow_sub;
        gl_lds16(&Kbase[(size_t)(kt0 + row) * E + ((kslot ^ (row & 7)) << 3)], &Ksl[c * 512]);
      }
    } else {
#pragma unroll
      for (int i = 0; i < 8; ++i) {
        int c = (w - 2) * 8 + i;
        int e = c * 16 + ve_sub;
        int lc = vchunk ^ ((e >> 1) & 3);
        gl_lds16(&Vbase[(size_t)e * NSEQ + kt0 + (lc << 3)], &Vsl[c * 512]);
      }
    }
  };

  stage(0, 0);
  __syncthreads();                     // tile 0 resident

  for (int t = 0; t < NT; ++t) {
    const int buf = t & 1;
    const bf16* Ksl = (const bf16*)(smem + buf * 32768);
    const bf16* Vsl = Ksl + 8192;

    // QK^T swapped: each kf feeds both q-halves
    f32x4 s0l = {}, s1l = {}, s0h = {}, s1h = {};
#pragma unroll
    for (int df = 0; df < 4; ++df) {
      const int slot = (((s << 4) + df * 4 + lhi) ^ swz) << 3;
      bf16x8 kf0 = *reinterpret_cast<const bf16x8*>(&Ksl[l15 * 256 + slot]);
      bf16x8 kf1 = *reinterpret_cast<const bf16x8*>(&Ksl[(16 + l15) * 256 + slot]);
      s0l = __builtin_amdgcn_mfma_f32_16x16x32_bf16(kf0, qlo[df], s0l, 0, 0, 0);
      s0h = __builtin_amdgcn_mfma_f32_16x16x32_bf16(kf0, qhi[df], s0h, 0, 0, 0);
      s1l = __builtin_amdgcn_mfma_f32_16x16x32_bf16(kf1, qlo[df], s1l, 0, 0, 0);
      s1h = __builtin_amdgcn_mfma_f32_16x16x32_bf16(kf1, qhi[df], s1h, 0, 0, 0);
    }

    // prefetch next tile: pinned so QK^T starts at barrier-exit; staging issue
    // overlaps the exp2 chain below.
    __builtin_amdgcn_sched_barrier(0);
    if (t + 1 < NT) stage(buf ^ 1, t + 1);
    __builtin_amdgcn_sched_barrier(0);

    // max-free softmax: P = 2^S for both q-halves
    bf16 pbl[8], pbh[8];
    float r0 = 0.f, r1 = 0.f;
#pragma unroll
    for (int r = 0; r < 4; ++r) {
      float e0 = __builtin_amdgcn_exp2f(s0l[r]);
      float e1 = __builtin_amdgcn_exp2f(s1l[r]);
      r0 += e0 + e1;
      pbl[r] = (bf16)e0;
      pbl[4 + r] = (bf16)e1;
      float e2 = __builtin_amdgcn_exp2f(s0h[r]);
      float e3 = __builtin_amdgcn_exp2f(s1h[r]);
      r1 += e2 + e3;
      pbh[r] = (bf16)e2;
      pbh[4 + r] = (bf16)e3;
    }
    ll0 += r0;
    ll1 += r1;
    bf16x8 pal = *reinterpret_cast<const bf16x8*>(pbl);
    bf16x8 pah = *reinterpret_cast<const bf16x8*>(pbh);

    __builtin_amdgcn_s_setprio(1);
#pragma unroll
    for (int eb = 0; eb < 16; ++eb) {
      bf16x8 vf = *reinterpret_cast<const bf16x8*>(&Vsl[(eb * 16 + l15) * 32 + voff]);
      olo[eb] = __builtin_amdgcn_mfma_f32_16x16x32_bf16(pal, vf, olo[eb], 0, 0, 0);
      ohi[eb] = __builtin_amdgcn_mfma_f32_16x16x32_bf16(pah, vf, ohi[eb], 0, 0, 0);
    }
    __builtin_amdgcn_s_setprio(0);

    __syncthreads();                   // drains next-tile loads; frees buf for overwrite
  }

  // epilogue: reduce l per half, cross-wave stream combine (bf16 Z) + RMS rinv + store
  ll0 += __shfl_xor(ll0, 16, 64);
  ll0 += __shfl_xor(ll0, 32, 64);
  ll1 += __shfl_xor(ll1, 16, 64);
  ll1 += __shfl_xor(ll1, 32, 64);
  float L0[4], L1[4];
#pragma unroll
  for (int r = 0; r < 4; ++r) {
    L0[r] = __shfl(ll0, 4 * lhi + r, 64);
    L1[r] = __shfl(ll1, 4 * lhi + r, 64);
  }

  bf16* Zg = Zb + g * 8192;            // [32 rows][256 e] bf16
  if (s) {
#pragma unroll
    for (int r = 0; r < 4; ++r) {
      float i2l = lam / L0[r];
      float i2h = lam / L1[r];
#pragma unroll
      for (int eb = 0; eb < 16; ++eb) {
        Zg[(4 * lhi + r) * 256 + eb * 16 + l15] = (bf16)(olo[eb][r] * i2l);
        Zg[(16 + 4 * lhi + r) * 256 + eb * 16 + l15] = (bf16)(ohi[eb][r] * i2h);
      }
    }
  }
  __syncthreads();
  if (!s) {
#pragma unroll
    for (int half = 0; half < 2; ++half) {
      const f32x4* oh = half ? ohi : olo;
      const float* Lh = half ? L1 : L0;
#pragma unroll
      for (int r = 0; r < 4; ++r) {
        float i1 = 1.0f / Lh[r];
        float vals[16];
        float ssq = 0.f;
#pragma unroll
        for (int eb = 0; eb < 16; ++eb) {
          float v = oh[eb][r] * i1 -
                    (float)Zg[(half * 16 + 4 * lhi + r) * 256 + eb * 16 + l15];
          vals[eb] = v;
          ssq += v * v;
        }
#pragma unroll
        for (int off = 1; off < 16; off <<= 1) ssq += __shfl_xor(ssq, off, 64);
        float rinv = rsqrtf(ssq * (1.0f / 256.0f) + RMS_EPS);
        const int q = q0 + g * 32 + half * 16 + 4 * lhi + r;
        const size_t ob = ((size_t)b * NSEQ + q) * E + (size_t)h * 256;
#pragma unroll
        for (int eb = 0; eb < 16; ++eb) {
          int e = eb * 16 + l15;
          Ob[ob + e] = (bf16)(vals[eb] * rinv);
        }
      }
    }
  }
}

// ---------------------------------------------------------------- launch
extern "C" void kernel_launch(void* const* d_in, const int* in_sizes, int n_in,
                              void* d_out, int out_size, void* d_ws, size_t ws_size,
                              hipStream_t stream) {
  const float* X   = (const float*)d_in[0];
  const float* Wq  = (const float*)d_in[1];
  const float* Wk  = (const float*)d_in[2];
  const float* Wv  = (const float*)d_in[3];
  const float* Wo  = (const float*)d_in[4];
  const float* lq1 = (const float*)d_in[5];
  const float* lk1 = (const float*)d_in[6];
  const float* lq2 = (const float*)d_in[7];
  const float* lk2 = (const float*)d_in[8];
  const float* rs  = (const float*)d_in[9];
  float* out = (float*)d_out;

  constexpr size_t B = 2, NSEQ = 2048, D = 1024, E = 2048;
  constexpr size_t M = B * NSEQ;  // 4096

  char* ws = (char*)d_ws;
  bf16* Xb  = (bf16*)ws;                 // M*D
  bf16* Wqb = Xb + M * D;                // E*D  (Wqb/Wkb/Wvb contiguous -> [6144][1024])
  bf16* Wkb = Wqb + E * D;
  bf16* Wvb = Wkb + E * D;
  bf16* Wob = Wvb + E * D;               // D*E (pre-scaled by rs*osc)
  bf16* Qb  = Wob + D * E;               // M*E  (Qb/Kb/Vtb contiguous for fused epilogue)
  bf16* Kb  = Qb + M * E;
  bf16* Vtb = Kb + M * E;                // M*E, layout [b,h,e,perm(n)]
  bf16* Ob  = Vtb + M * E;               // M*E

  fused_cast<<<2048, 256, 0, stream>>>(X, Wq, Wk, Wv, Wo, rs, Xb);

  gemm_bt<3, 128><<<dim3(M / 128, 6144 / 128), 256, 0, stream>>>(
      Xb, Wqb, Qb, (int)M, 6144, (int)D);

  diff_attn<<<dim3(512), 256, 0, stream>>>(Qb, Kb, Vtb, lq1, lk1, lq2, lk2, Ob);

  gemm_bt<1, 64><<<dim3(M / 64, D / 128), 256, 0, stream>>>(Ob, Wob, out, (int)M, (int)D, (int)E);
}

// Round 15
// 221.383 us; speedup vs baseline: 1.1442x; 1.0476x over previous
//
#include <hip/hip_runtime.h>
#include <hip/hip_bf16.h>

typedef __bf16 bf16;
typedef __attribute__((ext_vector_type(8))) __bf16 bf16x8;
typedef __attribute__((ext_vector_type(4))) float f32x4;

#define LAMBDA_INIT_F 0.3555090675909693f
#define RMS_EPS 1e-5f
// (1/sqrt(128)) * log2(e) : folded into Q so QK^T scores are ready for exp2
#define QSCALE_F 0.1275174053237f

__device__ __forceinline__ void gl_lds16(const bf16* g, bf16* l) {
  __builtin_amdgcn_global_load_lds(
      (const __attribute__((address_space(1))) unsigned int*)g,
      (__attribute__((address_space(3))) unsigned int*)l, 16, 0, 0);
}

// ---------------------------------------------------------------- fused cast f32 -> bf16
// Destinations contiguous in ws: Xb(4M) Wqb(2M) Wkb(2M) Wvb(2M) Wob(2M) elems.
// Wo region is pre-scaled by rms_scale[col&255] * (1-lambda_init).
__global__ void fused_cast(const float* __restrict__ X, const float* __restrict__ Wq,
                           const float* __restrict__ Wk, const float* __restrict__ Wv,
                           const float* __restrict__ Wo, const float* __restrict__ rs,
                           bf16* __restrict__ out) {
  constexpr int T4 = 3145728;          // 12M elems / 4
  constexpr float OSC = 1.0f - LAMBDA_INIT_F;
  int idx = blockIdx.x * blockDim.x + threadIdx.x;
  int stride = gridDim.x * blockDim.x;
  for (int i = idx; i < T4; i += stride) {
    const float* src;
    int off;
    bool isWo = false;
    if (i < 1048576)       { src = X;  off = i; }
    else if (i < 1572864)  { src = Wq; off = i - 1048576; }
    else if (i < 2097152)  { src = Wk; off = i - 1572864; }
    else if (i < 2621440)  { src = Wv; off = i - 2097152; }
    else                   { src = Wo; off = i - 2621440; isWo = true; }
    float4 v = reinterpret_cast<const float4*>(src)[off];
    if (isWo) {
      int r0 = (off * 4) & 255;        // col % 256 (row len 2048 divisible by 256)
      v.x *= rs[r0] * OSC; v.y *= rs[r0 + 1] * OSC;
      v.z *= rs[r0 + 2] * OSC; v.w *= rs[r0 + 3] * OSC;
    }
    bf16 o[4];
    o[0] = (bf16)v.x; o[1] = (bf16)v.y; o[2] = (bf16)v.z; o[3] = (bf16)v.w;
    *reinterpret_cast<ushort4*>(&out[(size_t)i * 4]) = *reinterpret_cast<const ushort4*>(o);
  }
}

// ---------------------------------------------------------------- bt-GEMM (global_load_lds, 2-phase dbuf, BK=64)
// C[m,n] = sum_k A[m,k] * B[n,k]
// BK=64: 128B LDS rows would be a 16-way bank conflict on the b128 fragment read,
// so slots are XOR-swizzled (slot ^= row&7) with the swizzle folded into the
// per-lane gl_lds16 SOURCE address (linear LDS dest) — same verified pattern as
// attention's K staging. Halves the barrier count vs BK=32.
// MODE 1: f32 row-major out.
// MODE 3: fused QKV epilogue (N=6144): region n>>11 == 0 -> Qb bf16 * QSCALE;
//         1 -> Kb bf16; 2 -> Vt[b,h,e, perm(nseq)] (key 16h+4g+c -> slot 8g+4h+c,
//         so attention's V staging is 16B-contiguous gl_lds16).
template <int MODE, int BM>
__global__ __launch_bounds__(256) void gemm_bt(
    const bf16* __restrict__ A, const bf16* __restrict__ B,
    void* __restrict__ Cv, int M, int N, int K) {
  constexpr int BN = 128, BK = 64;
  constexpr int MF = BM / 32;
  constexpr int CA = BM / 8;           // A chunks of 1KB (8 rows x 8 slots)
  __shared__ __align__(16) bf16 As[2][BM * BK];
  __shared__ __align__(16) bf16 Bs[2][BN * BK];
  const int tid = threadIdx.x, lane = tid & 63, w = tid >> 6;
  const int l15 = lane & 15, lhi = lane >> 4;
  const int wr = (w >> 1) * (BM / 2), wc = (w & 1) * 64;
  const int bm = blockIdx.x * BM, bn = blockIdx.y * BN;
  const int srow8 = lane >> 3;         // row within 1KB chunk (8 rows)
  const int sslot = lane & 7;          // 16B slot within 128B row
  const int NTK = K / BK;
  f32x4 acc[MF][4] = {};

  auto stage = [&](int buf, int k0) {
    // A: CA chunks, CA/4 per wave; source slot pre-swizzled (slot ^ row&7)
#pragma unroll
    for (int i = 0; i < CA / 4; ++i) {
      int c = w * (CA / 4) + i;
      int row = c * 8 + srow8;
      gl_lds16(&A[(size_t)(bm + row) * K + k0 + ((sslot ^ srow8) << 3)], &As[buf][c * 512]);
    }
    // B: 16 chunks, 4 per wave
#pragma unroll
    for (int i = 0; i < 4; ++i) {
      int c = w * 4 + i;
      int row = c * 8 + srow8;
      gl_lds16(&B[(size_t)(bn + row) * K + k0 + ((sslot ^ srow8) << 3)], &Bs[buf][c * 512]);
    }
  };

  stage(0, 0);
  __syncthreads();
  for (int t = 0; t < NTK; ++t) {
    const int buf = t & 1;
    if (t + 1 < NTK) stage(buf ^ 1, (t + 1) * BK);
#pragma unroll
    for (int kk = 0; kk < 2; ++kk) {
      bf16x8 af[MF], bfr[4];
#pragma unroll
      for (int mf = 0; mf < MF; ++mf) {
        int row = wr + mf * 16 + l15;
        af[mf] = *reinterpret_cast<const bf16x8*>(
            &As[buf][row * BK + (((kk * 4 + lhi) ^ (row & 7)) << 3)]);
      }
#pragma unroll
      for (int nf = 0; nf < 4; ++nf) {
        int row = wc + nf * 16 + l15;
        bfr[nf] = *reinterpret_cast<const bf16x8*>(
            &Bs[buf][row * BK + (((kk * 4 + lhi) ^ (row & 7)) << 3)]);
      }
#pragma unroll
      for (int mf = 0; mf < MF; ++mf)
#pragma unroll
        for (int nf = 0; nf < 4; ++nf)
          acc[mf][nf] = __builtin_amdgcn_mfma_f32_16x16x32_bf16(af[mf], bfr[nf], acc[mf][nf], 0, 0, 0);
    }
    __syncthreads();
  }

#pragma unroll
  for (int mf = 0; mf < MF; ++mf)
#pragma unroll
    for (int nf = 0; nf < 4; ++nf)
#pragma unroll
      for (int r = 0; r < 4; ++r) {
        int m = bm + wr + mf * 16 + lhi * 4 + r;
        int n = bn + wc + nf * 16 + l15;
        if constexpr (MODE == 1) {
          ((float*)Cv)[(size_t)m * N + n] = acc[mf][nf][r];
        } else {
          int reg = n >> 11, nl = n & 2047;
          if (reg == 0) {
            ((bf16*)Cv)[(size_t)m * 2048 + nl] = (bf16)(acc[mf][nf][r] * QSCALE_F);
          } else if (reg == 1) {
            ((bf16*)Cv)[(size_t)(m + 4096) * 2048 + nl] = (bf16)acc[mf][nf][r];
          } else {
            // Vt[b, h, e, perm(nseq)] at Cv + 2*M*2048
            int bb = m >> 11, nq = m & 2047;
            int hh = nl >> 8, e = nl & 255;
            int k5 = nq & 31;
            int slot = (((k5 >> 2) & 3) << 3) | (((k5 >> 4) & 1) << 2) | (k5 & 3);
            int np = (nq & ~31) | slot;
            ((bf16*)Cv)[(size_t)16777216 + ((((size_t)bb * 8 + hh) * 256 + e) << 11) + np] =
                (bf16)acc[mf][nf][r];
          }
        }
      }
}

// ---------------------------------------------------------------- differential flash attention
// 1D grid 512 (XCD-chunk swizzled), block 256 = 4 waves: q-group g=w>>1 (32 rows),
// stream s=w&1. q-tile = 64 rows. Each wave owns 32 q-rows of ONE stream as two
// 16-row halves: every K/V fragment read feeds 2 MFMAs (halved per-FLOP LDS traffic),
// P fully in-lane. Swapped QK^T; max-free softmax via exp2 (Q pre-scaled by SC*log2e);
// per-lane partial l per half, reduced in epilogue. K LDS [32][256] w/ 16B-slot XOR
// swizzle in gl_lds16 source; V slot-permuted global -> 16B-contiguous staging with
// chunk bank-swizzle. Double-buffered, one barrier/tile, stage pinned mid-iteration.
// RMS scale & (1-lambda_init) folded into Wo: epilogue applies rinv only.
__global__ __launch_bounds__(256, 2) void diff_attn(
    const bf16* __restrict__ Q, const bf16* __restrict__ Kb, const bf16* __restrict__ Vtg,
    const float* __restrict__ lq1, const float* __restrict__ lk1,
    const float* __restrict__ lq2, const float* __restrict__ lk2,
    bf16* __restrict__ Ob) {
  constexpr int NSEQ = 2048, E = 2048, KT = 32, NT = NSEQ / KT;
  __shared__ __align__(16) char smem[65536];   // 2 x (K 16KB + V 16KB); epilogue: Zb[2][32][256] bf16
  bf16* Zb = (bf16*)smem;

  const int tid = threadIdx.x, lane = tid & 63, w = tid >> 6;
  const int l15 = lane & 15, lhi = lane >> 4;
  const int g = w >> 1, s = w & 1;

  // XCD-chunk swizzle: XCD k owns orig [k*64, (k+1)*64) -> 2 head-instances per XCD
  const int bid = blockIdx.x;
  const int orig = (bid & 7) * 64 + (bid >> 3);
  const int bh = orig >> 5;
  const int qb = orig & 31;
  const int b = bh >> 3, h = bh & 7;
  const int q0 = qb * 64;

  float lam = 0.f;
  if (s) {
    float sl1 = 0.f, sl2 = 0.f;
    for (int i = 0; i < 128; ++i) {
      sl1 += lq1[h * 128 + i] * lk1[h * 128 + i];
      sl2 += lq2[h * 128 + i] * lk2[h * 128 + i];
    }
    lam = __expf(sl1) - __expf(sl2) + LAMBDA_INIT_F;
  }

  // Q frags for the wave's two q-halves (B-operand: col=q, k=lhi*8+j)
  const size_t qbase = ((size_t)b * NSEQ + q0 + g * 32 + l15) * E + (size_t)h * 256 + s * 128;
  bf16x8 qlo[4], qhi[4];
#pragma unroll
  for (int df = 0; df < 4; ++df) {
    qlo[df] = *reinterpret_cast<const bf16x8*>(&Q[qbase + df * 32 + lhi * 8]);
    qhi[df] = *reinterpret_cast<const bf16x8*>(&Q[qbase + 16 * E + df * 32 + lhi * 8]);
  }

  const bf16* Kbase = Kb + ((size_t)b * NSEQ) * E + (size_t)h * 256;
  const bf16* Vbase = Vtg + (((size_t)b * 8 + h) * 256) * (size_t)NSEQ;

  // staging invariants
  const int krow_sub = lane >> 5;      // 0/1: row within 1KB K chunk
  const int kslot = lane & 31;         // 16B slot in 512B K row
  const int ve_sub = lane >> 2;        // 0..15: e-row within 1KB V chunk
  const int vchunk = lane & 3;         // 16B chunk within 64B V row
  const int swz = l15 & 7;
  const int vq2 = (l15 >> 1) & 3;      // V read swizzle key
  const int voff = (lhi ^ vq2) << 3;   // element offset of 16B within V row

  f32x4 olo[16] = {}, ohi[16] = {};
  float ll0 = 0.f, ll1 = 0.f;

  // 32 chunks of 1KB per tile (16 K + 16 V) over 4 waves: 8 per wave
  auto stage = [&](int buf, int t) {
    const int kt0 = t * KT;
    bf16* Ksl = (bf16*)(smem + buf * 32768);
    bf16* Vsl = Ksl + 8192;
    if (w < 2) {
#pragma unroll
      for (int i = 0; i < 8; ++i) {
        int c = w * 8 + i;
        int row = 2 * c + krow_sub;
        gl_lds16(&Kbase[(size_t)(kt0 + row) * E + ((kslot ^ (row & 7)) << 3)], &Ksl[c * 512]);
      }
    } else {
#pragma unroll
      for (int i = 0; i < 8; ++i) {
        int c = (w - 2) * 8 + i;
        int e = c * 16 + ve_sub;
        int lc = vchunk ^ ((e >> 1) & 3);
        gl_lds16(&Vbase[(size_t)e * NSEQ + kt0 + (lc << 3)], &Vsl[c * 512]);
      }
    }
  };

  stage(0, 0);
  __syncthreads();                     // tile 0 resident

  for (int t = 0; t < NT; ++t) {
    const int buf = t & 1;
    const bf16* Ksl = (const bf16*)(smem + buf * 32768);
    const bf16* Vsl = Ksl + 8192;

    // QK^T swapped: each kf feeds both q-halves
    f32x4 s0l = {}, s1l = {}, s0h = {}, s1h = {};
#pragma unroll
    for (int df = 0; df < 4; ++df) {
      const int slot = (((s << 4) + df * 4 + lhi) ^ swz) << 3;
      bf16x8 kf0 = *reinterpret_cast<const bf16x8*>(&Ksl[l15 * 256 + slot]);
      bf16x8 kf1 = *reinterpret_cast<const bf16x8*>(&Ksl[(16 + l15) * 256 + slot]);
      s0l = __builtin_amdgcn_mfma_f32_16x16x32_bf16(kf0, qlo[df], s0l, 0, 0, 0);
      s0h = __builtin_amdgcn_mfma_f32_16x16x32_bf16(kf0, qhi[df], s0h, 0, 0, 0);
      s1l = __builtin_amdgcn_mfma_f32_16x16x32_bf16(kf1, qlo[df], s1l, 0, 0, 0);
      s1h = __builtin_amdgcn_mfma_f32_16x16x32_bf16(kf1, qhi[df], s1h, 0, 0, 0);
    }

    // prefetch next tile: pinned so QK^T starts at barrier-exit; staging issue
    // overlaps the exp2 chain below.
    __builtin_amdgcn_sched_barrier(0);
    if (t + 1 < NT) stage(buf ^ 1, t + 1);
    __builtin_amdgcn_sched_barrier(0);

    // max-free softmax: P = 2^S for both q-halves
    bf16 pbl[8], pbh[8];
    float r0 = 0.f, r1 = 0.f;
#pragma unroll
    for (int r = 0; r < 4; ++r) {
      float e0 = __builtin_amdgcn_exp2f(s0l[r]);
      float e1 = __builtin_amdgcn_exp2f(s1l[r]);
      r0 += e0 + e1;
      pbl[r] = (bf16)e0;
      pbl[4 + r] = (bf16)e1;
      float e2 = __builtin_amdgcn_exp2f(s0h[r]);
      float e3 = __builtin_amdgcn_exp2f(s1h[r]);
      r1 += e2 + e3;
      pbh[r] = (bf16)e2;
      pbh[4 + r] = (bf16)e3;
    }
    ll0 += r0;
    ll1 += r1;
    bf16x8 pal = *reinterpret_cast<const bf16x8*>(pbl);
    bf16x8 pah = *reinterpret_cast<const bf16x8*>(pbh);

    __builtin_amdgcn_s_setprio(1);
#pragma unroll
    for (int eb = 0; eb < 16; ++eb) {
      bf16x8 vf = *reinterpret_cast<const bf16x8*>(&Vsl[(eb * 16 + l15) * 32 + voff]);
      olo[eb] = __builtin_amdgcn_mfma_f32_16x16x32_bf16(pal, vf, olo[eb], 0, 0, 0);
      ohi[eb] = __builtin_amdgcn_mfma_f32_16x16x32_bf16(pah, vf, ohi[eb], 0, 0, 0);
    }
    __builtin_amdgcn_s_setprio(0);

    __syncthreads();                   // drains next-tile loads; frees buf for overwrite
  }

  // epilogue: reduce l per half, cross-wave stream combine (bf16 Z) + RMS rinv + store
  ll0 += __shfl_xor(ll0, 16, 64);
  ll0 += __shfl_xor(ll0, 32, 64);
  ll1 += __shfl_xor(ll1, 16, 64);
  ll1 += __shfl_xor(ll1, 32, 64);
  float L0[4], L1[4];
#pragma unroll
  for (int r = 0; r < 4; ++r) {
    L0[r] = __shfl(ll0, 4 * lhi + r, 64);
    L1[r] = __shfl(ll1, 4 * lhi + r, 64);
  }

  bf16* Zg = Zb + g * 8192;            // [32 rows][256 e] bf16
  if (s) {
#pragma unroll
    for (int r = 0; r < 4; ++r) {
      float i2l = lam / L0[r];
      float i2h = lam / L1[r];
#pragma unroll
      for (int eb = 0; eb < 16; ++eb) {
        Zg[(4 * lhi + r) * 256 + eb * 16 + l15] = (bf16)(olo[eb][r] * i2l);
        Zg[(16 + 4 * lhi + r) * 256 + eb * 16 + l15] = (bf16)(ohi[eb][r] * i2h);
      }
    }
  }
  __syncthreads();
  if (!s) {
#pragma unroll
    for (int half = 0; half < 2; ++half) {
      const f32x4* oh = half ? ohi : olo;
      const float* Lh = half ? L1 : L0;
#pragma unroll
      for (int r = 0; r < 4; ++r) {
        float i1 = 1.0f / Lh[r];
        float vals[16];
        float ssq = 0.f;
#pragma unroll
        for (int eb = 0; eb < 16; ++eb) {
          float v = oh[eb][r] * i1 -
                    (float)Zg[(half * 16 + 4 * lhi + r) * 256 + eb * 16 + l15];
          vals[eb] = v;
          ssq += v * v;
        }
#pragma unroll
        for (int off = 1; off < 16; off <<= 1) ssq += __shfl_xor(ssq, off, 64);
        float rinv = rsqrtf(ssq * (1.0f / 256.0f) + RMS_EPS);
        const int q = q0 + g * 32 + half * 16 + 4 * lhi + r;
        const size_t ob = ((size_t)b * NSEQ + q) * E + (size_t)h * 256;
#pragma unroll
        for (int eb = 0; eb < 16; ++eb) {
          int e = eb * 16 + l15;
          Ob[ob + e] = (bf16)(vals[eb] * rinv);
        }
      }
    }
  }
}

// ---------------------------------------------------------------- launch
extern "C" void kernel_launch(void* const* d_in, const int* in_sizes, int n_in,
                              void* d_out, int out_size, void* d_ws, size_t ws_size,
                              hipStream_t stream) {
  const float* X   = (const float*)d_in[0];
  const float* Wq  = (const float*)d_in[1];
  const float* Wk  = (const float*)d_in[2];
  const float* Wv  = (const float*)d_in[3];
  const float* Wo  = (const float*)d_in[4];
  const float* lq1 = (const float*)d_in[5];
  const float* lk1 = (const float*)d_in[6];
  const float* lq2 = (const float*)d_in[7];
  const float* lk2 = (const float*)d_in[8];
  const float* rs  = (const float*)d_in[9];
  float* out = (float*)d_out;

  constexpr size_t B = 2, NSEQ = 2048, D = 1024, E = 2048;
  constexpr size_t M = B * NSEQ;  // 4096

  char* ws = (char*)d_ws;
  bf16* Xb  = (bf16*)ws;                 // M*D
  bf16* Wqb = Xb + M * D;                // E*D  (Wqb/Wkb/Wvb contiguous -> [6144][1024])
  bf16* Wkb = Wqb + E * D;
  bf16* Wvb = Wkb + E * D;
  bf16* Wob = Wvb + E * D;               // D*E (pre-scaled by rs*osc)
  bf16* Qb  = Wob + D * E;               // M*E  (Qb/Kb/Vtb contiguous for fused epilogue)
  bf16* Kb  = Qb + M * E;
  bf16* Vtb = Kb + M * E;                // M*E, layout [b,h,e,perm(n)]
  bf16* Ob  = Vtb + M * E;               // M*E

  fused_cast<<<2048, 256, 0, stream>>>(X, Wq, Wk, Wv, Wo, rs, Xb);

  gemm_bt<3, 128><<<dim3(M / 128, 6144 / 128), 256, 0, stream>>>(
      Xb, Wqb, Qb, (int)M, 6144, (int)D);

  diff_attn<<<dim3(512), 256, 0, stream>>>(Qb, Kb, Vtb, lq1, lk1, lq2, lk2, Ob);

  gemm_bt<1, 64><<<dim3(M / 64, D / 128), 256, 0, stream>>>(Ob, Wob, out, (int)M, (int)D, (int)E);
}

// Round 16
// 220.319 us; speedup vs baseline: 1.1497x; 1.0048x over previous
//
#include <hip/hip_runtime.h>
#include <hip/hip_bf16.h>

typedef __bf16 bf16;
typedef __attribute__((ext_vector_type(8))) __bf16 bf16x8;
typedef __attribute__((ext_vector_type(4))) float f32x4;

#define LAMBDA_INIT_F 0.3555090675909693f
#define RMS_EPS 1e-5f
// (1/sqrt(128)) * log2(e) : folded into Q so QK^T scores are ready for exp2
#define QSCALE_F 0.1275174053237f

__device__ __forceinline__ void gl_lds16(const bf16* g, bf16* l) {
  __builtin_amdgcn_global_load_lds(
      (const __attribute__((address_space(1))) unsigned int*)g,
      (__attribute__((address_space(3))) unsigned int*)l, 16, 0, 0);
}

// ---------------------------------------------------------------- fused cast f32 -> bf16
// Destinations contiguous in ws: Xb(4M) Wqb(2M) Wkb(2M) Wvb(2M) Wob(2M) elems.
// Wo region is pre-scaled by rms_scale[col&255] * (1-lambda_init).
__global__ void fused_cast(const float* __restrict__ X, const float* __restrict__ Wq,
                           const float* __restrict__ Wk, const float* __restrict__ Wv,
                           const float* __restrict__ Wo, const float* __restrict__ rs,
                           bf16* __restrict__ out) {
  constexpr int T4 = 3145728;          // 12M elems / 4
  constexpr float OSC = 1.0f - LAMBDA_INIT_F;
  int idx = blockIdx.x * blockDim.x + threadIdx.x;
  int stride = gridDim.x * blockDim.x;
  for (int i = idx; i < T4; i += stride) {
    const float* src;
    int off;
    bool isWo = false;
    if (i < 1048576)       { src = X;  off = i; }
    else if (i < 1572864)  { src = Wq; off = i - 1048576; }
    else if (i < 2097152)  { src = Wk; off = i - 1572864; }
    else if (i < 2621440)  { src = Wv; off = i - 2097152; }
    else                   { src = Wo; off = i - 2621440; isWo = true; }
    float4 v = reinterpret_cast<const float4*>(src)[off];
    if (isWo) {
      int r0 = (off * 4) & 255;        // col % 256 (row len 2048 divisible by 256)
      v.x *= rs[r0] * OSC; v.y *= rs[r0 + 1] * OSC;
      v.z *= rs[r0 + 2] * OSC; v.w *= rs[r0 + 3] * OSC;
    }
    bf16 o[4];
    o[0] = (bf16)v.x; o[1] = (bf16)v.y; o[2] = (bf16)v.z; o[3] = (bf16)v.w;
    *reinterpret_cast<ushort4*>(&out[(size_t)i * 4]) = *reinterpret_cast<const ushort4*>(o);
  }
}

// ---------------------------------------------------------------- bt-GEMM (global_load_lds, 2-phase dbuf, BK=64)
// C[m,n] = sum_k A[m,k] * B[n,k]
// BK=64: 128B LDS rows would be a 16-way bank conflict on the b128 fragment read,
// so slots are XOR-swizzled (slot ^= row&7) with the swizzle folded into the
// per-lane gl_lds16 SOURCE address (linear LDS dest).
// MODE 1: f32 row-major out.
// MODE 3: fused QKV epilogue (N=6144): region n>>11 == 0 -> Qb bf16 * QSCALE;
//         1 -> Kb bf16; 2 -> Vt[b,h,e, perm(nseq)] (key 16h+4g+c -> slot 8g+4h+c,
//         so attention's V staging is 16B-contiguous gl_lds16).
template <int MODE, int BM>
__global__ __launch_bounds__(256) void gemm_bt(
    const bf16* __restrict__ A, const bf16* __restrict__ B,
    void* __restrict__ Cv, int M, int N, int K) {
  constexpr int BN = 128, BK = 64;
  constexpr int MF = BM / 32;
  constexpr int CA = BM / 8;           // A chunks of 1KB (8 rows x 8 slots)
  __shared__ __align__(16) bf16 As[2][BM * BK];
  __shared__ __align__(16) bf16 Bs[2][BN * BK];
  const int tid = threadIdx.x, lane = tid & 63, w = tid >> 6;
  const int l15 = lane & 15, lhi = lane >> 4;
  const int wr = (w >> 1) * (BM / 2), wc = (w & 1) * 64;
  const int bm = blockIdx.x * BM, bn = blockIdx.y * BN;
  const int srow8 = lane >> 3;         // row within 1KB chunk (8 rows)
  const int sslot = lane & 7;          // 16B slot within 128B row
  const int NTK = K / BK;
  f32x4 acc[MF][4] = {};

  auto stage = [&](int buf, int k0) {
#pragma unroll
    for (int i = 0; i < CA / 4; ++i) {
      int c = w * (CA / 4) + i;
      int row = c * 8 + srow8;
      gl_lds16(&A[(size_t)(bm + row) * K + k0 + ((sslot ^ srow8) << 3)], &As[buf][c * 512]);
    }
#pragma unroll
    for (int i = 0; i < 4; ++i) {
      int c = w * 4 + i;
      int row = c * 8 + srow8;
      gl_lds16(&B[(size_t)(bn + row) * K + k0 + ((sslot ^ srow8) << 3)], &Bs[buf][c * 512]);
    }
  };

  stage(0, 0);
  __syncthreads();
  for (int t = 0; t < NTK; ++t) {
    const int buf = t & 1;
    if (t + 1 < NTK) stage(buf ^ 1, (t + 1) * BK);
#pragma unroll
    for (int kk = 0; kk < 2; ++kk) {
      bf16x8 af[MF], bfr[4];
#pragma unroll
      for (int mf = 0; mf < MF; ++mf) {
        int row = wr + mf * 16 + l15;
        af[mf] = *reinterpret_cast<const bf16x8*>(
            &As[buf][row * BK + (((kk * 4 + lhi) ^ (row & 7)) << 3)]);
      }
#pragma unroll
      for (int nf = 0; nf < 4; ++nf) {
        int row = wc + nf * 16 + l15;
        bfr[nf] = *reinterpret_cast<const bf16x8*>(
            &Bs[buf][row * BK + (((kk * 4 + lhi) ^ (row & 7)) << 3)]);
      }
#pragma unroll
      for (int mf = 0; mf < MF; ++mf)
#pragma unroll
        for (int nf = 0; nf < 4; ++nf)
          acc[mf][nf] = __builtin_amdgcn_mfma_f32_16x16x32_bf16(af[mf], bfr[nf], acc[mf][nf], 0, 0, 0);
    }
    __syncthreads();
  }

#pragma unroll
  for (int mf = 0; mf < MF; ++mf)
#pragma unroll
    for (int nf = 0; nf < 4; ++nf)
#pragma unroll
      for (int r = 0; r < 4; ++r) {
        int m = bm + wr + mf * 16 + lhi * 4 + r;
        int n = bn + wc + nf * 16 + l15;
        if constexpr (MODE == 1) {
          ((float*)Cv)[(size_t)m * N + n] = acc[mf][nf][r];
        } else {
          int reg = n >> 11, nl = n & 2047;
          if (reg == 0) {
            ((bf16*)Cv)[(size_t)m * 2048 + nl] = (bf16)(acc[mf][nf][r] * QSCALE_F);
          } else if (reg == 1) {
            ((bf16*)Cv)[(size_t)(m + 4096) * 2048 + nl] = (bf16)acc[mf][nf][r];
          } else {
            // Vt[b, h, e, perm(nseq)] at Cv + 2*M*2048
            int bb = m >> 11, nq = m & 2047;
            int hh = nl >> 8, e = nl & 255;
            int k5 = nq & 31;
            int slot = (((k5 >> 2) & 3) << 3) | (((k5 >> 4) & 1) << 2) | (k5 & 3);
            int np = (nq & ~31) | slot;
            ((bf16*)Cv)[(size_t)16777216 + ((((size_t)bb * 8 + hh) * 256 + e) << 11) + np] =
                (bf16)acc[mf][nf][r];
          }
        }
      }
}

// ---------------------------------------------------------------- differential flash attention
// 1D grid 512 (XCD-chunk swizzled), block 256 = 4 waves: q-group g=w>>1 (32 rows),
// stream s=w&1. q-tile = 64 rows. Each wave owns 32 q-rows of ONE stream as two
// 16-row halves: every K/V fragment read feeds 2 MFMAs (halved per-FLOP LDS traffic),
// P fully in-lane. Swapped QK^T; max-free softmax via exp2 (Q pre-scaled by SC*log2e);
// per-lane partial l per half, reduced in epilogue. K LDS [32][256] w/ 16B-slot XOR
// swizzle in gl_lds16 source; V slot-permuted global -> 16B-contiguous staging with
// chunk bank-swizzle. Double-buffered, one barrier/tile, stage pinned mid-iteration.
// setprio(1) wraps both MFMA clusters. RMS scale & (1-lambda_init) folded into Wo.
// Epilogue is SPLIT across the stream-wave pair: each stream publishes its
// contribution for the PARTNER's 16 rows (scaled by its own 1/L -> no L exchange),
// then each wave finalizes (combine + RMS + store) its own 16 rows.
__global__ __launch_bounds__(256, 2) void diff_attn(
    const bf16* __restrict__ Q, const bf16* __restrict__ Kb, const bf16* __restrict__ Vtg,
    const float* __restrict__ lq1, const float* __restrict__ lk1,
    const float* __restrict__ lq2, const float* __restrict__ lk2,
    bf16* __restrict__ Ob) {
  constexpr int NSEQ = 2048, E = 2048, KT = 32, NT = NSEQ / KT;
  __shared__ __align__(16) char smem[65536];   // 2 x (K 16KB + V 16KB); epilogue: Zb[2][32][256] bf16
  bf16* Zb = (bf16*)smem;

  const int tid = threadIdx.x, lane = tid & 63, w = tid >> 6;
  const int l15 = lane & 15, lhi = lane >> 4;
  const int g = w >> 1, s = w & 1;

  // XCD-chunk swizzle: XCD k owns orig [k*64, (k+1)*64) -> 2 head-instances per XCD
  const int bid = blockIdx.x;
  const int orig = (bid & 7) * 64 + (bid >> 3);
  const int bh = orig >> 5;
  const int qb = orig & 31;
  const int b = bh >> 3, h = bh & 7;
  const int q0 = qb * 64;

  float lam = 0.f;
  if (s) {
    float sl1 = 0.f, sl2 = 0.f;
    for (int i = 0; i < 128; ++i) {
      sl1 += lq1[h * 128 + i] * lk1[h * 128 + i];
      sl2 += lq2[h * 128 + i] * lk2[h * 128 + i];
    }
    lam = __expf(sl1) - __expf(sl2) + LAMBDA_INIT_F;
  }

  // Q frags for the wave's two q-halves (B-operand: col=q, k=lhi*8+j)
  const size_t qbase = ((size_t)b * NSEQ + q0 + g * 32 + l15) * E + (size_t)h * 256 + s * 128;
  bf16x8 qlo[4], qhi[4];
#pragma unroll
  for (int df = 0; df < 4; ++df) {
    qlo[df] = *reinterpret_cast<const bf16x8*>(&Q[qbase + df * 32 + lhi * 8]);
    qhi[df] = *reinterpret_cast<const bf16x8*>(&Q[qbase + 16 * E + df * 32 + lhi * 8]);
  }

  const bf16* Kbase = Kb + ((size_t)b * NSEQ) * E + (size_t)h * 256;
  const bf16* Vbase = Vtg + (((size_t)b * 8 + h) * 256) * (size_t)NSEQ;

  // staging invariants
  const int krow_sub = lane >> 5;      // 0/1: row within 1KB K chunk
  const int kslot = lane & 31;         // 16B slot in 512B K row
  const int ve_sub = lane >> 2;        // 0..15: e-row within 1KB V chunk
  const int vchunk = lane & 3;         // 16B chunk within 64B V row
  const int swz = l15 & 7;
  const int vq2 = (l15 >> 1) & 3;      // V read swizzle key
  const int voff = (lhi ^ vq2) << 3;   // element offset of 16B within V row

  f32x4 olo[16] = {}, ohi[16] = {};
  float ll0 = 0.f, ll1 = 0.f;

  // 32 chunks of 1KB per tile (16 K + 16 V) over 4 waves: 8 per wave
  auto stage = [&](int buf, int t) {
    const int kt0 = t * KT;
    bf16* Ksl = (bf16*)(smem + buf * 32768);
    bf16* Vsl = Ksl + 8192;
    if (w < 2) {
#pragma unroll
      for (int i = 0; i < 8; ++i) {
        int c = w * 8 + i;
        int row = 2 * c + krow_sub;
        gl_lds16(&Kbase[(size_t)(kt0 + row) * E + ((kslot ^ (row & 7)) << 3)], &Ksl[c * 512]);
      }
    } else {
#pragma unroll
      for (int i = 0; i < 8; ++i) {
        int c = (w - 2) * 8 + i;
        int e = c * 16 + ve_sub;
        int lc = vchunk ^ ((e >> 1) & 3);
        gl_lds16(&Vbase[(size_t)e * NSEQ + kt0 + (lc << 3)], &Vsl[c * 512]);
      }
    }
  };

  stage(0, 0);
  __syncthreads();                     // tile 0 resident

  for (int t = 0; t < NT; ++t) {
    const int buf = t & 1;
    const bf16* Ksl = (const bf16*)(smem + buf * 32768);
    const bf16* Vsl = Ksl + 8192;

    // QK^T swapped: each kf feeds both q-halves
    f32x4 s0l = {}, s1l = {}, s0h = {}, s1h = {};
    __builtin_amdgcn_s_setprio(1);
#pragma unroll
    for (int df = 0; df < 4; ++df) {
      const int slot = (((s << 4) + df * 4 + lhi) ^ swz) << 3;
      bf16x8 kf0 = *reinterpret_cast<const bf16x8*>(&Ksl[l15 * 256 + slot]);
      bf16x8 kf1 = *reinterpret_cast<const bf16x8*>(&Ksl[(16 + l15) * 256 + slot]);
      s0l = __builtin_amdgcn_mfma_f32_16x16x32_bf16(kf0, qlo[df], s0l, 0, 0, 0);
      s0h = __builtin_amdgcn_mfma_f32_16x16x32_bf16(kf0, qhi[df], s0h, 0, 0, 0);
      s1l = __builtin_amdgcn_mfma_f32_16x16x32_bf16(kf1, qlo[df], s1l, 0, 0, 0);
      s1h = __builtin_amdgcn_mfma_f32_16x16x32_bf16(kf1, qhi[df], s1h, 0, 0, 0);
    }
    __builtin_amdgcn_s_setprio(0);

    // prefetch next tile: pinned so QK^T starts at barrier-exit; staging issue
    // overlaps the exp2 chain below.
    __builtin_amdgcn_sched_barrier(0);
    if (t + 1 < NT) stage(buf ^ 1, t + 1);
    __builtin_amdgcn_sched_barrier(0);

    // max-free softmax: P = 2^S for both q-halves
    bf16 pbl[8], pbh[8];
    float r0 = 0.f, r1 = 0.f;
#pragma unroll
    for (int r = 0; r < 4; ++r) {
      float e0 = __builtin_amdgcn_exp2f(s0l[r]);
      float e1 = __builtin_amdgcn_exp2f(s1l[r]);
      r0 += e0 + e1;
      pbl[r] = (bf16)e0;
      pbl[4 + r] = (bf16)e1;
      float e2 = __builtin_amdgcn_exp2f(s0h[r]);
      float e3 = __builtin_amdgcn_exp2f(s1h[r]);
      r1 += e2 + e3;
      pbh[r] = (bf16)e2;
      pbh[4 + r] = (bf16)e3;
    }
    ll0 += r0;
    ll1 += r1;
    bf16x8 pal = *reinterpret_cast<const bf16x8*>(pbl);
    bf16x8 pah = *reinterpret_cast<const bf16x8*>(pbh);

    __builtin_amdgcn_s_setprio(1);
#pragma unroll
    for (int eb = 0; eb < 16; ++eb) {
      bf16x8 vf = *reinterpret_cast<const bf16x8*>(&Vsl[(eb * 16 + l15) * 32 + voff]);
      olo[eb] = __builtin_amdgcn_mfma_f32_16x16x32_bf16(pal, vf, olo[eb], 0, 0, 0);
      ohi[eb] = __builtin_amdgcn_mfma_f32_16x16x32_bf16(pah, vf, ohi[eb], 0, 0, 0);
    }
    __builtin_amdgcn_s_setprio(0);

    __syncthreads();                   // drains next-tile loads; frees buf for overwrite
  }

  // epilogue: reduce l per half; each stream publishes its contribution for the
  // PARTNER's 16 rows (scaled by own 1/L), then finalizes its own 16 rows.
  //   stream0 (!s) finalizes rows 0-15 (lo half), publishes rows 16-31 (hi half).
  //   stream1 ( s) finalizes rows 16-31 (hi half), publishes rows 0-15 (lo half).
  ll0 += __shfl_xor(ll0, 16, 64);
  ll0 += __shfl_xor(ll0, 32, 64);
  ll1 += __shfl_xor(ll1, 16, 64);
  ll1 += __shfl_xor(ll1, 32, 64);
  float L0[4], L1[4];
#pragma unroll
  for (int r = 0; r < 4; ++r) {
    L0[r] = __shfl(ll0, 4 * lhi + r, 64);   // lo-half l for row 4*lhi+r
    L1[r] = __shfl(ll1, 4 * lhi + r, 64);   // hi-half l for row 16 + 4*lhi+r
  }

  bf16* Zg = Zb + g * 8192;            // [32 rows][256 e] bf16
  if (s) {
    // publish stream-1 contribution for lo rows: lam * o2 / L
#pragma unroll
    for (int r = 0; r < 4; ++r) {
      float i2 = lam / L0[r];
#pragma unroll
      for (int eb = 0; eb < 16; ++eb)
        Zg[(4 * lhi + r) * 256 + eb * 16 + l15] = (bf16)(olo[eb][r] * i2);
    }
  } else {
    // publish stream-0 contribution for hi rows: o1 / L
#pragma unroll
    for (int r = 0; r < 4; ++r) {
      float i1 = 1.0f / L1[r];
#pragma unroll
      for (int eb = 0; eb < 16; ++eb)
        Zg[(16 + 4 * lhi + r) * 256 + eb * 16 + l15] = (bf16)(ohi[eb][r] * i1);
    }
  }
  __syncthreads();
  {
    // finalize own 16 rows: v = (stream0 term) - (stream1 term)
    const int rowbase = s ? 16 : 0;
#pragma unroll
    for (int r = 0; r < 4; ++r) {
      float vals[16];
      float ssq = 0.f;
      if (!s) {
        float i1 = 1.0f / L0[r];
#pragma unroll
        for (int eb = 0; eb < 16; ++eb) {
          float v = olo[eb][r] * i1 - (float)Zg[(4 * lhi + r) * 256 + eb * 16 + l15];
          vals[eb] = v;
          ssq += v * v;
        }
      } else {
        float i2 = lam / L1[r];
#pragma unroll
        for (int eb = 0; eb < 16; ++eb) {
          float v = (float)Zg[(16 + 4 * lhi + r) * 256 + eb * 16 + l15] - ohi[eb][r] * i2;
          vals[eb] = v;
          ssq += v * v;
        }
      }
#pragma unroll
      for (int off = 1; off < 16; off <<= 1) ssq += __shfl_xor(ssq, off, 64);
      float rinv = rsqrtf(ssq * (1.0f / 256.0f) + RMS_EPS);
      const int q = q0 + g * 32 + rowbase + 4 * lhi + r;
      const size_t ob = ((size_t)b * NSEQ + q) * E + (size_t)h * 256;
#pragma unroll
      for (int eb = 0; eb < 16; ++eb) {
        int e = eb * 16 + l15;
        Ob[ob + e] = (bf16)(vals[eb] * rinv);
      }
    }
  }
}

// ---------------------------------------------------------------- launch
extern "C" void kernel_launch(void* const* d_in, const int* in_sizes, int n_in,
                              void* d_out, int out_size, void* d_ws, size_t ws_size,
                              hipStream_t stream) {
  const float* X   = (const float*)d_in[0];
  const float* Wq  = (const float*)d_in[1];
  const float* Wk  = (const float*)d_in[2];
  const float* Wv  = (const float*)d_in[3];
  const float* Wo  = (const float*)d_in[4];
  const float* lq1 = (const float*)d_in[5];
  const float* lk1 = (const float*)d_in[6];
  const float* lq2 = (const float*)d_in[7];
  const float* lk2 = (const float*)d_in[8];
  const float* rs  = (const float*)d_in[9];
  float* out = (float*)d_out;

  constexpr size_t B = 2, NSEQ = 2048, D = 1024, E = 2048;
  constexpr size_t M = B * NSEQ;  // 4096

  char* ws = (char*)d_ws;
  bf16* Xb  = (bf16*)ws;                 // M*D
  bf16* Wqb = Xb + M * D;                // E*D  (Wqb/Wkb/Wvb contiguous -> [6144][1024])
  bf16* Wkb = Wqb + E * D;
  bf16* Wvb = Wkb + E * D;
  bf16* Wob = Wvb + E * D;               // D*E (pre-scaled by rs*osc)
  bf16* Qb  = Wob + D * E;               // M*E  (Qb/Kb/Vtb contiguous for fused epilogue)
  bf16* Kb  = Qb + M * E;
  bf16* Vtb = Kb + M * E;                // M*E, layout [b,h,e,perm(n)]
  bf16* Ob  = Vtb + M * E;               // M*E

  fused_cast<<<2048, 256, 0, stream>>>(X, Wq, Wk, Wv, Wo, rs, Xb);

  gemm_bt<3, 128><<<dim3(M / 128, 6144 / 128), 256, 0, stream>>>(
      Xb, Wqb, Qb, (int)M, 6144, (int)D);

  diff_attn<<<dim3(512), 256, 0, stream>>>(Qb, Kb, Vtb, lq1, lk1, lq2, lk2, Ob);

  gemm_bt<1, 64><<<dim3(M / 64, D / 128), 256, 0, stream>>>(Ob, Wob, out, (int)M, (int)D, (int)E);
}